// Round 1
// baseline (12166.753 us; speedup 1.0000x reference)
//
#include <hip/hip_runtime.h>

#define N_USERS 100000
#define N_ITEMS 50000
#define N_NODES 150000
#define EMB_DIM 64
#define N_EDGES 4800000
#define N_LAYERS 3

// ---------------------------------------------------------------------------
// init: cur = concat(emb_user, emb_item); acc(d_out) = same
// float4-vectorized: N_NODES*64/4 = 2.4M float4 elements
// ---------------------------------------------------------------------------
__global__ void init_kernel(const float* __restrict__ emb_user,
                            const float* __restrict__ emb_item,
                            float* __restrict__ cur,
                            float* __restrict__ acc) {
    int i = blockIdx.x * blockDim.x + threadIdx.x;
    const int total = N_NODES * EMB_DIM / 4;
    if (i >= total) return;
    const int user_f4 = N_USERS * EMB_DIM / 4;
    float4 v;
    if (i < user_f4) {
        v = reinterpret_cast<const float4*>(emb_user)[i];
    } else {
        v = reinterpret_cast<const float4*>(emb_item)[i - user_f4];
    }
    reinterpret_cast<float4*>(cur)[i] = v;
    reinterpret_cast<float4*>(acc)[i] = v;
}

// ---------------------------------------------------------------------------
// scatter: for each edge e: next[row[e]] += val[e] * cur[col[e]]
// 16 threads per edge, each thread owns a float4 chunk (4 atomics).
// ---------------------------------------------------------------------------
__global__ void scatter_kernel(const int* __restrict__ edge_row,
                               const int* __restrict__ edge_col,
                               const float* __restrict__ edge_val,
                               const float* __restrict__ x,
                               float* __restrict__ y) {
    long long tid = (long long)blockIdx.x * blockDim.x + threadIdx.x;
    long long e = tid >> 4;
    int sub = (int)(tid & 15);
    if (e >= N_EDGES) return;

    int r = edge_row[e];
    int c = edge_col[e];
    float v = edge_val[e];

    float4 xv = reinterpret_cast<const float4*>(x)[(long long)c * 16 + sub];
    float* dst = y + ((long long)r * EMB_DIM + sub * 4);
    atomicAdd(dst + 0, v * xv.x);
    atomicAdd(dst + 1, v * xv.y);
    atomicAdd(dst + 2, v * xv.z);
    atomicAdd(dst + 3, v * xv.w);
}

// ---------------------------------------------------------------------------
// acc += next (float4), optional final *0.25
// ---------------------------------------------------------------------------
template <bool FINAL>
__global__ void add_kernel(const float* __restrict__ nxt,
                           float* __restrict__ acc) {
    int i = blockIdx.x * blockDim.x + threadIdx.x;
    const int total = N_NODES * EMB_DIM / 4;
    if (i >= total) return;
    float4 a = reinterpret_cast<float4*>(acc)[i];
    float4 b = reinterpret_cast<const float4*>(nxt)[i];
    a.x += b.x; a.y += b.y; a.z += b.z; a.w += b.w;
    if (FINAL) {
        const float s = 1.0f / (N_LAYERS + 1);
        a.x *= s; a.y *= s; a.z *= s; a.w *= s;
    }
    reinterpret_cast<float4*>(acc)[i] = a;
}

extern "C" void kernel_launch(void* const* d_in, const int* in_sizes, int n_in,
                              void* d_out, int out_size, void* d_ws, size_t ws_size,
                              hipStream_t stream) {
    const float* emb_user = (const float*)d_in[0];
    const float* emb_item = (const float*)d_in[1];
    const int*   edge_row = (const int*)d_in[2];
    const int*   edge_col = (const int*)d_in[3];
    const float* edge_val = (const float*)d_in[4];
    float* acc = (float*)d_out;

    const size_t buf_elems = (size_t)N_NODES * EMB_DIM;          // 9.6M floats
    const size_t buf_bytes = buf_elems * sizeof(float);          // 38.4 MB
    float* bufA = (float*)d_ws;
    float* bufB = bufA + buf_elems;

    const int BT = 256;
    const int total_f4 = N_NODES * EMB_DIM / 4;                  // 2.4M
    const int grid_f4 = (total_f4 + BT - 1) / BT;

    // init: cur = bufA = emb, acc = emb
    init_kernel<<<grid_f4, BT, 0, stream>>>(emb_user, emb_item, bufA, acc);

    const long long scatter_threads = (long long)N_EDGES * 16;   // 76.8M
    const int grid_sc = (int)((scatter_threads + BT - 1) / BT);

    float* cur = bufA;
    float* nxt = bufB;
    for (int layer = 0; layer < N_LAYERS; ++layer) {
        hipMemsetAsync(nxt, 0, buf_bytes, stream);
        scatter_kernel<<<grid_sc, BT, 0, stream>>>(edge_row, edge_col, edge_val,
                                                   cur, nxt);
        if (layer == N_LAYERS - 1) {
            add_kernel<true><<<grid_f4, BT, 0, stream>>>(nxt, acc);
        } else {
            add_kernel<false><<<grid_f4, BT, 0, stream>>>(nxt, acc);
        }
        float* t = cur; cur = nxt; nxt = t;
    }
}

// Round 2
// 1111.427 us; speedup vs baseline: 10.9470x; 10.9470x over previous
//
#include <hip/hip_runtime.h>

#define N_USERS 100000
#define N_ITEMS 50000
#define N_NODES 150000
#define EMB_DIM 64
#define N_EDGES 4800000
#define N_LAYERS 3

#define SCAN_CHUNK 1024
#define N_SCAN_BLOCKS ((N_NODES + SCAN_CHUNK - 1) / SCAN_CHUNK)  // 147

// ---------------------------------------------------------------------------
// init: cur = concat(emb_user, emb_item); acc(d_out) = same
// ---------------------------------------------------------------------------
__global__ void init_kernel(const float* __restrict__ emb_user,
                            const float* __restrict__ emb_item,
                            float* __restrict__ cur,
                            float* __restrict__ acc) {
    int i = blockIdx.x * blockDim.x + threadIdx.x;
    const int total = N_NODES * EMB_DIM / 4;
    if (i >= total) return;
    const int user_f4 = N_USERS * EMB_DIM / 4;
    float4 v;
    if (i < user_f4) {
        v = reinterpret_cast<const float4*>(emb_user)[i];
    } else {
        v = reinterpret_cast<const float4*>(emb_item)[i - user_f4];
    }
    reinterpret_cast<float4*>(cur)[i] = v;
    reinterpret_cast<float4*>(acc)[i] = v;
}

// ---------------------------------------------------------------------------
// CSR construction
// ---------------------------------------------------------------------------
__global__ void hist_kernel(const int* __restrict__ row, int* __restrict__ cnt) {
    int i = blockIdx.x * blockDim.x + threadIdx.x;
    int stride = gridDim.x * blockDim.x;
    for (int e = i; e < N_EDGES / 4; e += stride) {
        int4 r = reinterpret_cast<const int4*>(row)[e];
        atomicAdd(&cnt[r.x], 1);
        atomicAdd(&cnt[r.y], 1);
        atomicAdd(&cnt[r.z], 1);
        atomicAdd(&cnt[r.w], 1);
    }
}

// per-block (1024-elem chunk) sums
__global__ void scan_pass1(const int* __restrict__ cnt, int* __restrict__ blockSums) {
    __shared__ int wsum[4];
    int b = blockIdx.x, t = threadIdx.x;
    int lane = t & 63, wave = t >> 6;
    int i0 = b * SCAN_CHUNK + t * 4;
    int s = 0;
    if (i0 + 3 < N_NODES) {
        int4 v = *reinterpret_cast<const int4*>(cnt + i0);
        s = v.x + v.y + v.z + v.w;
    } else {
        for (int k = 0; k < 4; ++k) if (i0 + k < N_NODES) s += cnt[i0 + k];
    }
    for (int off = 32; off > 0; off >>= 1) s += __shfl_down(s, off, 64);
    if (lane == 0) wsum[wave] = s;
    __syncthreads();
    if (t == 0) blockSums[b] = wsum[0] + wsum[1] + wsum[2] + wsum[3];
}

// exclusive scan of the 147 block sums (single block)
__global__ void scan_pass2(int* __restrict__ blockSums, int* __restrict__ total_out) {
    __shared__ int lds[256];
    int t = threadIdx.x;
    int v = (t < N_SCAN_BLOCKS) ? blockSums[t] : 0;
    lds[t] = v;
    __syncthreads();
    for (int off = 1; off < 256; off <<= 1) {
        int x = (t >= off) ? lds[t - off] : 0;
        __syncthreads();
        lds[t] += x;
        __syncthreads();
    }
    int incl = lds[t];
    if (t < N_SCAN_BLOCKS) blockSums[t] = incl - v;   // exclusive block offset
    if (t == 255) *total_out = incl;                   // = N_EDGES
}

// full exclusive scan -> row_ptr and cursor
__global__ void scan_pass3(const int* __restrict__ cnt, const int* __restrict__ blockSums,
                           int* __restrict__ row_ptr, int* __restrict__ cursor) {
    __shared__ int wsum[4];
    int b = blockIdx.x, t = threadIdx.x;
    int lane = t & 63, wave = t >> 6;
    int i0 = b * SCAN_CHUNK + t * 4;
    int v0 = 0, v1 = 0, v2 = 0, v3 = 0;
    bool full = (i0 + 3 < N_NODES);
    if (full) {
        int4 v = *reinterpret_cast<const int4*>(cnt + i0);
        v0 = v.x; v1 = v.y; v2 = v.z; v3 = v.w;
    } else {
        if (i0 + 0 < N_NODES) v0 = cnt[i0 + 0];
        if (i0 + 1 < N_NODES) v1 = cnt[i0 + 1];
        if (i0 + 2 < N_NODES) v2 = cnt[i0 + 2];
    }
    int tsum = v0 + v1 + v2 + v3;
    int x = tsum;
    for (int off = 1; off < 64; off <<= 1) {
        int y = __shfl_up(x, off, 64);
        if (lane >= off) x += y;
    }
    if (lane == 63) wsum[wave] = x;
    __syncthreads();
    int woff = 0;
    for (int w = 0; w < wave; ++w) woff += wsum[w];
    int base = blockSums[b] + woff + (x - tsum);   // exclusive start for this thread
    int p0 = base, p1 = base + v0, p2 = base + v0 + v1, p3 = base + v0 + v1 + v2;
    if (full) {
        int4 p = make_int4(p0, p1, p2, p3);
        *reinterpret_cast<int4*>(row_ptr + i0) = p;
        *reinterpret_cast<int4*>(cursor + i0) = p;
    } else {
        if (i0 + 0 < N_NODES) { row_ptr[i0 + 0] = p0; cursor[i0 + 0] = p0; }
        if (i0 + 1 < N_NODES) { row_ptr[i0 + 1] = p1; cursor[i0 + 1] = p1; }
        if (i0 + 2 < N_NODES) { row_ptr[i0 + 2] = p2; cursor[i0 + 2] = p2; }
    }
}

// scatter edges into row-sorted (col, val) pairs
__global__ void permute_kernel(const int* __restrict__ row, const int* __restrict__ col,
                               const float* __restrict__ val, int* __restrict__ cursor,
                               int2* __restrict__ cv) {
    int i = blockIdx.x * blockDim.x + threadIdx.x;
    int stride = gridDim.x * blockDim.x;
    for (int e = i; e < N_EDGES / 4; e += stride) {
        int4 r = reinterpret_cast<const int4*>(row)[e];
        int4 c = reinterpret_cast<const int4*>(col)[e];
        float4 v = reinterpret_cast<const float4*>(val)[e];
        int s0 = atomicAdd(&cursor[r.x], 1);
        cv[s0] = make_int2(c.x, __float_as_int(v.x));
        int s1 = atomicAdd(&cursor[r.y], 1);
        cv[s1] = make_int2(c.y, __float_as_int(v.y));
        int s2 = atomicAdd(&cursor[r.z], 1);
        cv[s2] = make_int2(c.z, __float_as_int(v.z));
        int s3 = atomicAdd(&cursor[r.w], 1);
        cv[s3] = make_int2(c.w, __float_as_int(v.w));
    }
}

// ---------------------------------------------------------------------------
// gather SpMM: one wave per row; 4 edges/iter; 16-lane group per edge.
// MODE 0: y = A*x, acc += y.   MODE 1: acc = (acc + A*x) * 0.25 (y unused)
// ---------------------------------------------------------------------------
template <int MODE>
__global__ void spmm_kernel(const int* __restrict__ row_ptr,
                            const int2* __restrict__ cv,
                            const float* __restrict__ x,
                            float* __restrict__ y,
                            float* __restrict__ acc) {
    int wave = threadIdx.x >> 6;
    int lane = threadIdx.x & 63;
    int r = blockIdx.x * 4 + wave;
    if (r >= N_NODES) return;
    int g = lane >> 4;   // which edge of the chunk
    int d = lane & 15;   // which float4 of the embedding
    int s = row_ptr[r];
    int e = row_ptr[r + 1];
    const float4* xf4 = reinterpret_cast<const float4*>(x);
    float4 a4 = make_float4(0.f, 0.f, 0.f, 0.f);
    for (int j = s; j < e; j += 4) {
        int idx = j + g;
        bool ok = idx < e;
        int2 cvv = cv[ok ? idx : s];
        float v = ok ? __int_as_float(cvv.y) : 0.f;
        float4 xv = xf4[(cvv.x << 4) + d];
        a4.x += v * xv.x;
        a4.y += v * xv.y;
        a4.z += v * xv.z;
        a4.w += v * xv.w;
    }
    // reduce the 4 edge-groups
    for (int off = 16; off <= 32; off <<= 1) {
        a4.x += __shfl_xor(a4.x, off, 64);
        a4.y += __shfl_xor(a4.y, off, 64);
        a4.z += __shfl_xor(a4.z, off, 64);
        a4.w += __shfl_xor(a4.w, off, 64);
    }
    if (g == 0) {
        int o = (r << 4) + d;
        float4* af4 = reinterpret_cast<float4*>(acc);
        float4 a = af4[o];
        if (MODE == 0) {
            reinterpret_cast<float4*>(y)[o] = a4;
            a.x += a4.x; a.y += a4.y; a.z += a4.z; a.w += a4.w;
            af4[o] = a;
        } else {
            const float sc = 1.0f / (N_LAYERS + 1);
            a.x = (a.x + a4.x) * sc;
            a.y = (a.y + a4.y) * sc;
            a.z = (a.z + a4.z) * sc;
            a.w = (a.w + a4.w) * sc;
            af4[o] = a;
        }
    }
}

// ---------------------------------------------------------------------------
// fallback (round-0) atomic path, used only if ws_size is too small
// ---------------------------------------------------------------------------
__global__ void scatter_kernel(const int* __restrict__ edge_row,
                               const int* __restrict__ edge_col,
                               const float* __restrict__ edge_val,
                               const float* __restrict__ x,
                               float* __restrict__ y) {
    long long tid = (long long)blockIdx.x * blockDim.x + threadIdx.x;
    long long e = tid >> 4;
    int sub = (int)(tid & 15);
    if (e >= N_EDGES) return;
    int r = edge_row[e];
    int c = edge_col[e];
    float v = edge_val[e];
    float4 xv = reinterpret_cast<const float4*>(x)[(long long)c * 16 + sub];
    float* dst = y + ((long long)r * EMB_DIM + sub * 4);
    atomicAdd(dst + 0, v * xv.x);
    atomicAdd(dst + 1, v * xv.y);
    atomicAdd(dst + 2, v * xv.z);
    atomicAdd(dst + 3, v * xv.w);
}

template <bool FINAL>
__global__ void add_kernel(const float* __restrict__ nxt, float* __restrict__ acc) {
    int i = blockIdx.x * blockDim.x + threadIdx.x;
    const int total = N_NODES * EMB_DIM / 4;
    if (i >= total) return;
    float4 a = reinterpret_cast<float4*>(acc)[i];
    float4 b = reinterpret_cast<const float4*>(nxt)[i];
    a.x += b.x; a.y += b.y; a.z += b.z; a.w += b.w;
    if (FINAL) {
        const float s = 1.0f / (N_LAYERS + 1);
        a.x *= s; a.y *= s; a.z *= s; a.w *= s;
    }
    reinterpret_cast<float4*>(acc)[i] = a;
}

// ---------------------------------------------------------------------------
extern "C" void kernel_launch(void* const* d_in, const int* in_sizes, int n_in,
                              void* d_out, int out_size, void* d_ws, size_t ws_size,
                              hipStream_t stream) {
    const float* emb_user = (const float*)d_in[0];
    const float* emb_item = (const float*)d_in[1];
    const int*   edge_row = (const int*)d_in[2];
    const int*   edge_col = (const int*)d_in[3];
    const float* edge_val = (const float*)d_in[4];
    float* acc = (float*)d_out;

    const size_t buf_elems = (size_t)N_NODES * EMB_DIM;          // 9.6M floats
    const size_t buf_bytes = buf_elems * sizeof(float);          // 38.4 MB

    // workspace layout (CSR path)
    float* bufA = (float*)d_ws;
    float* bufB = bufA + buf_elems;
    int2*  cv   = (int2*)(bufB + buf_elems);
    int*   row_ptr = (int*)((char*)cv + (size_t)N_EDGES * sizeof(int2));
    int*   cursor  = row_ptr + (N_NODES + 4);                    // padded
    int*   blockSums = cursor + N_NODES;
    size_t need = (char*)(blockSums + 256) - (char*)d_ws;

    const int BT = 256;
    const int total_f4 = N_NODES * EMB_DIM / 4;
    const int grid_f4 = (total_f4 + BT - 1) / BT;

    if (ws_size >= need) {
        // ---- CSR build ----
        hipMemsetAsync(cursor, 0, (size_t)N_NODES * sizeof(int), stream);
        hist_kernel<<<2048, BT, 0, stream>>>(edge_row, cursor);
        scan_pass1<<<N_SCAN_BLOCKS, BT, 0, stream>>>(cursor, blockSums);
        scan_pass2<<<1, BT, 0, stream>>>(blockSums, row_ptr + N_NODES);
        scan_pass3<<<N_SCAN_BLOCKS, BT, 0, stream>>>(cursor, blockSums, row_ptr, cursor);
        permute_kernel<<<2048, BT, 0, stream>>>(edge_row, edge_col, edge_val, cursor, cv);

        // ---- init + 3 gather layers ----
        init_kernel<<<grid_f4, BT, 0, stream>>>(emb_user, emb_item, bufA, acc);
        const int grid_rows = (N_NODES + 3) / 4;    // 4 waves/block, 1 row/wave
        spmm_kernel<0><<<grid_rows, BT, 0, stream>>>(row_ptr, cv, bufA, bufB, acc);
        spmm_kernel<0><<<grid_rows, BT, 0, stream>>>(row_ptr, cv, bufB, bufA, acc);
        spmm_kernel<1><<<grid_rows, BT, 0, stream>>>(row_ptr, cv, bufA, bufB, acc);
    } else {
        // ---- fallback: atomic scatter path ----
        init_kernel<<<grid_f4, BT, 0, stream>>>(emb_user, emb_item, bufA, acc);
        const long long scatter_threads = (long long)N_EDGES * 16;
        const int grid_sc = (int)((scatter_threads + BT - 1) / BT);
        float* cur = bufA;
        float* nxt = bufB;
        for (int layer = 0; layer < N_LAYERS; ++layer) {
            hipMemsetAsync(nxt, 0, buf_bytes, stream);
            scatter_kernel<<<grid_sc, BT, 0, stream>>>(edge_row, edge_col, edge_val, cur, nxt);
            if (layer == N_LAYERS - 1) {
                add_kernel<true><<<grid_f4, BT, 0, stream>>>(nxt, acc);
            } else {
                add_kernel<false><<<grid_f4, BT, 0, stream>>>(nxt, acc);
            }
            float* t = cur; cur = nxt; nxt = t;
        }
    }
}

// Round 3
// 648.379 us; speedup vs baseline: 18.7649x; 1.7142x over previous
//
#include <hip/hip_runtime.h>

#define N_USERS 100000
#define N_ITEMS 50000
#define N_NODES 150000
#define EMB_DIM 64
#define N_EDGES 4800000
#define N_LAYERS 3

#define NB 586            // ceil(150000 / 256) buckets, bucket = row >> 8
#define CHUNK_I4 4096     // 16384 edges per pass_a block

__device__ __forceinline__ ushort f2bf(float f) {
    unsigned int b = __float_as_uint(f);
    unsigned int r = (b + 0x7FFFu + ((b >> 16) & 1u)) >> 16;   // RNE
    return (ushort)r;
}
__device__ __forceinline__ float bf2f(ushort u) {
    return __uint_as_float(((unsigned int)u) << 16);
}

// ---------------------------------------------------------------------------
// init: acc(d_out) = concat(emb) fp32; xA = concat(emb) bf16
// ---------------------------------------------------------------------------
__global__ void init_kernel(const float* __restrict__ emb_user,
                            const float* __restrict__ emb_item,
                            ushort* __restrict__ xA,
                            float* __restrict__ acc) {
    int i = blockIdx.x * blockDim.x + threadIdx.x;
    const int total = N_NODES * EMB_DIM / 4;
    if (i >= total) return;
    const int user_f4 = N_USERS * EMB_DIM / 4;
    float4 v;
    if (i < user_f4) {
        v = reinterpret_cast<const float4*>(emb_user)[i];
    } else {
        v = reinterpret_cast<const float4*>(emb_item)[i - user_f4];
    }
    reinterpret_cast<float4*>(acc)[i] = v;
    ushort4 h;
    h.x = f2bf(v.x); h.y = f2bf(v.y); h.z = f2bf(v.z); h.w = f2bf(v.w);
    reinterpret_cast<ushort4*>(xA)[i] = h;
}

// ---------------------------------------------------------------------------
// K1: global bucket histogram (LDS-staged)
// ---------------------------------------------------------------------------
__global__ void bucket_hist(const int* __restrict__ row, int* __restrict__ bucket_cnt) {
    __shared__ int cnt[NB];
    int t = threadIdx.x;
    for (int b = t; b < NB; b += 256) cnt[b] = 0;
    __syncthreads();
    int i = blockIdx.x * blockDim.x + t;
    int stride = gridDim.x * blockDim.x;
    for (int e = i; e < N_EDGES / 4; e += stride) {
        int4 r = reinterpret_cast<const int4*>(row)[e];
        atomicAdd(&cnt[r.x >> 8], 1);
        atomicAdd(&cnt[r.y >> 8], 1);
        atomicAdd(&cnt[r.z >> 8], 1);
        atomicAdd(&cnt[r.w >> 8], 1);
    }
    __syncthreads();
    for (int b = t; b < NB; b += 256) {
        int c = cnt[b];
        if (c) atomicAdd(&bucket_cnt[b], c);
    }
}

// ---------------------------------------------------------------------------
// K2: exclusive scan of 586 bucket counts (one 1024-thread block)
// ---------------------------------------------------------------------------
__global__ void bucket_scan(const int* __restrict__ bucket_cnt,
                            int* __restrict__ bucket_ptr,
                            int* __restrict__ bucket_cursor,
                            int* __restrict__ row_ptr) {
    __shared__ int lds[1024];
    int t = threadIdx.x;
    int v = (t < NB) ? bucket_cnt[t] : 0;
    lds[t] = v;
    __syncthreads();
    for (int off = 1; off < 1024; off <<= 1) {
        int x = (t >= off) ? lds[t - off] : 0;
        __syncthreads();
        lds[t] += x;
        __syncthreads();
    }
    int incl = lds[t];
    int excl = incl - v;
    if (t < NB) { bucket_ptr[t] = excl; bucket_cursor[t] = excl; }
    if (t == NB - 1) bucket_ptr[NB] = incl;
    if (t == 0) row_ptr[N_NODES] = N_EDGES;
}

// ---------------------------------------------------------------------------
// K3 (pass A): bin edges into bucket-contiguous regions.
// Per block: LDS hist of its chunk -> one reserve atomic per bucket -> scatter.
// ---------------------------------------------------------------------------
__global__ void pass_a(const int* __restrict__ row, const int* __restrict__ col,
                       const float* __restrict__ val,
                       int* __restrict__ bucket_cursor,
                       int* __restrict__ tmp_r, int2* __restrict__ tmp_cv) {
    __shared__ int cnt[NB];
    __shared__ int cur[NB];
    int t = threadIdx.x;
    int start = blockIdx.x * CHUNK_I4;
    int end = start + CHUNK_I4;
    if (end > N_EDGES / 4) end = N_EDGES / 4;
    for (int b = t; b < NB; b += 256) cnt[b] = 0;
    __syncthreads();
    for (int i = start + t; i < end; i += 256) {
        int4 r = reinterpret_cast<const int4*>(row)[i];
        atomicAdd(&cnt[r.x >> 8], 1);
        atomicAdd(&cnt[r.y >> 8], 1);
        atomicAdd(&cnt[r.z >> 8], 1);
        atomicAdd(&cnt[r.w >> 8], 1);
    }
    __syncthreads();
    for (int b = t; b < NB; b += 256) {
        int c = cnt[b];
        cur[b] = c ? atomicAdd(&bucket_cursor[b], c) : 0;
    }
    __syncthreads();
    for (int i = start + t; i < end; i += 256) {
        int4 r = reinterpret_cast<const int4*>(row)[i];
        int4 c = reinterpret_cast<const int4*>(col)[i];
        float4 v = reinterpret_cast<const float4*>(val)[i];
        int p;
        p = atomicAdd(&cur[r.x >> 8], 1); tmp_r[p] = r.x; tmp_cv[p] = make_int2(c.x, __float_as_int(v.x));
        p = atomicAdd(&cur[r.y >> 8], 1); tmp_r[p] = r.y; tmp_cv[p] = make_int2(c.y, __float_as_int(v.y));
        p = atomicAdd(&cur[r.z >> 8], 1); tmp_r[p] = r.z; tmp_cv[p] = make_int2(c.z, __float_as_int(v.z));
        p = atomicAdd(&cur[r.w >> 8], 1); tmp_r[p] = r.w; tmp_cv[p] = make_int2(c.w, __float_as_int(v.w));
    }
}

// ---------------------------------------------------------------------------
// K4 (pass B): per-bucket row sort. One block per bucket (256 rows).
// Also emits row_ptr. cv writes stay in an L2-resident ~65KB region.
// ---------------------------------------------------------------------------
__global__ void pass_b(const int* __restrict__ bucket_ptr,
                       const int* __restrict__ tmp_r, const int2* __restrict__ tmp_cv,
                       int* __restrict__ row_ptr, int2* __restrict__ cv) {
    __shared__ int cnt[256];
    __shared__ int cur[256];
    __shared__ int wtot[4];
    int t = threadIdx.x;
    int b = blockIdx.x;
    int bp = bucket_ptr[b], be = bucket_ptr[b + 1];
    cnt[t] = 0;
    __syncthreads();
    for (int e = bp + t; e < be; e += 256) atomicAdd(&cnt[tmp_r[e] & 255], 1);
    __syncthreads();
    int v = cnt[t];
    int lane = t & 63, wv = t >> 6;
    int x = v;
    for (int off = 1; off < 64; off <<= 1) {
        int y = __shfl_up(x, off, 64);
        if (lane >= off) x += y;
    }
    if (lane == 63) wtot[wv] = x;
    __syncthreads();
    int woff = 0;
    for (int w = 0; w < wv; ++w) woff += wtot[w];
    int excl = x + woff - v;            // exclusive scan of cnt
    int gr = (b << 8) + t;
    if (gr < N_NODES) row_ptr[gr] = bp + excl;
    cur[t] = bp + excl;
    __syncthreads();
    for (int e = bp + t; e < be; e += 256) {
        int r = tmp_r[e];
        int pos = atomicAdd(&cur[r & 255], 1);
        cv[pos] = tmp_cv[e];
    }
}

// ---------------------------------------------------------------------------
// gather SpMM (bf16 x): one wave per row; 16-lane group per edge, 4 edges/iter.
// MODE 0: y = bf16(A*x), acc += A*x.   MODE 1: acc = (acc + A*x) * 0.25
// ---------------------------------------------------------------------------
template <int MODE>
__global__ void spmm_kernel(const int* __restrict__ row_ptr,
                            const int2* __restrict__ cv,
                            const ushort* __restrict__ x,
                            ushort* __restrict__ y,
                            float* __restrict__ acc) {
    int wave = threadIdx.x >> 6;
    int lane = threadIdx.x & 63;
    int r = blockIdx.x * 4 + wave;
    if (r >= N_NODES) return;
    int g = lane >> 4;   // edge slot
    int d = lane & 15;   // ushort4 slot of the embedding row
    int s = row_ptr[r];
    int e = row_ptr[r + 1];
    const ushort4* xu = reinterpret_cast<const ushort4*>(x);
    float4 a4 = make_float4(0.f, 0.f, 0.f, 0.f);
    for (int j = s; j < e; j += 4) {
        int idx = j + g;
        bool ok = idx < e;
        int2 cvv = cv[ok ? idx : s];
        float v = ok ? __int_as_float(cvv.y) : 0.f;
        ushort4 xv = xu[(cvv.x << 4) + d];
        a4.x += v * bf2f(xv.x);
        a4.y += v * bf2f(xv.y);
        a4.z += v * bf2f(xv.z);
        a4.w += v * bf2f(xv.w);
    }
    for (int off = 16; off <= 32; off <<= 1) {
        a4.x += __shfl_xor(a4.x, off, 64);
        a4.y += __shfl_xor(a4.y, off, 64);
        a4.z += __shfl_xor(a4.z, off, 64);
        a4.w += __shfl_xor(a4.w, off, 64);
    }
    if (g == 0) {
        int o = (r << 4) + d;
        float4* af4 = reinterpret_cast<float4*>(acc);
        float4 a = af4[o];
        if (MODE == 0) {
            ushort4 h;
            h.x = f2bf(a4.x); h.y = f2bf(a4.y); h.z = f2bf(a4.z); h.w = f2bf(a4.w);
            reinterpret_cast<ushort4*>(y)[o] = h;
            a.x += a4.x; a.y += a4.y; a.z += a4.z; a.w += a4.w;
            af4[o] = a;
        } else {
            const float sc = 1.0f / (N_LAYERS + 1);
            a.x = (a.x + a4.x) * sc;
            a.y = (a.y + a4.y) * sc;
            a.z = (a.z + a4.z) * sc;
            a.w = (a.w + a4.w) * sc;
            af4[o] = a;
        }
    }
}

// ---------------------------------------------------------------------------
// fallback (round-0) atomic path, used only if ws_size is too small
// ---------------------------------------------------------------------------
__global__ void fb_init(const float* __restrict__ emb_user,
                        const float* __restrict__ emb_item,
                        float* __restrict__ cur, float* __restrict__ acc) {
    int i = blockIdx.x * blockDim.x + threadIdx.x;
    const int total = N_NODES * EMB_DIM / 4;
    if (i >= total) return;
    const int user_f4 = N_USERS * EMB_DIM / 4;
    float4 v;
    if (i < user_f4) v = reinterpret_cast<const float4*>(emb_user)[i];
    else             v = reinterpret_cast<const float4*>(emb_item)[i - user_f4];
    reinterpret_cast<float4*>(cur)[i] = v;
    reinterpret_cast<float4*>(acc)[i] = v;
}

__global__ void scatter_kernel(const int* __restrict__ edge_row,
                               const int* __restrict__ edge_col,
                               const float* __restrict__ edge_val,
                               const float* __restrict__ x,
                               float* __restrict__ y) {
    long long tid = (long long)blockIdx.x * blockDim.x + threadIdx.x;
    long long e = tid >> 4;
    int sub = (int)(tid & 15);
    if (e >= N_EDGES) return;
    int r = edge_row[e];
    int c = edge_col[e];
    float v = edge_val[e];
    float4 xv = reinterpret_cast<const float4*>(x)[(long long)c * 16 + sub];
    float* dst = y + ((long long)r * EMB_DIM + sub * 4);
    atomicAdd(dst + 0, v * xv.x);
    atomicAdd(dst + 1, v * xv.y);
    atomicAdd(dst + 2, v * xv.z);
    atomicAdd(dst + 3, v * xv.w);
}

template <bool FINAL>
__global__ void add_kernel(const float* __restrict__ nxt, float* __restrict__ acc) {
    int i = blockIdx.x * blockDim.x + threadIdx.x;
    const int total = N_NODES * EMB_DIM / 4;
    if (i >= total) return;
    float4 a = reinterpret_cast<float4*>(acc)[i];
    float4 b = reinterpret_cast<const float4*>(nxt)[i];
    a.x += b.x; a.y += b.y; a.z += b.z; a.w += b.w;
    if (FINAL) {
        const float s = 1.0f / (N_LAYERS + 1);
        a.x *= s; a.y *= s; a.z *= s; a.w *= s;
    }
    reinterpret_cast<float4*>(acc)[i] = a;
}

// ---------------------------------------------------------------------------
extern "C" void kernel_launch(void* const* d_in, const int* in_sizes, int n_in,
                              void* d_out, int out_size, void* d_ws, size_t ws_size,
                              hipStream_t stream) {
    const float* emb_user = (const float*)d_in[0];
    const float* emb_item = (const float*)d_in[1];
    const int*   edge_row = (const int*)d_in[2];
    const int*   edge_col = (const int*)d_in[3];
    const float* edge_val = (const float*)d_in[4];
    float* acc = (float*)d_out;

    // ---- workspace layout ----
    char* base = (char*)d_ws;
    int2* cv = (int2*)base;                                        // 38.4 MB
    char* scratch = base + (size_t)N_EDGES * sizeof(int2);
    int*  tmp_r  = (int*)scratch;                                  // 19.2 MB
    int2* tmp_cv = (int2*)(scratch + (size_t)N_EDGES * sizeof(int)); // 38.4 MB
    // xA/xB alias the tmp region (dead after pass_b; init runs after)
    ushort* xA = (ushort*)scratch;                                 // 19.2 MB
    ushort* xB = (ushort*)(scratch + (size_t)N_NODES * EMB_DIM * sizeof(ushort));
    char* meta = scratch + (size_t)N_EDGES * 12;                   // +57.6 MB
    int* row_ptr       = (int*)meta;                               // N_NODES+1
    int* bucket_cnt    = row_ptr + N_NODES + 2;
    int* bucket_ptr    = bucket_cnt + NB;                          // NB+1
    int* bucket_cursor = bucket_ptr + NB + 1;
    size_t need = (size_t)((char*)(bucket_cursor + NB) - base);

    const int BT = 256;
    const int total_f4 = N_NODES * EMB_DIM / 4;
    const int grid_f4 = (total_f4 + BT - 1) / BT;

    if (ws_size >= need) {
        // ---- bucketed counting sort -> row-sorted (col,val) + row_ptr ----
        hipMemsetAsync(bucket_cnt, 0, NB * sizeof(int), stream);
        bucket_hist<<<512, BT, 0, stream>>>(edge_row, bucket_cnt);
        bucket_scan<<<1, 1024, 0, stream>>>(bucket_cnt, bucket_ptr, bucket_cursor, row_ptr);
        const int grid_a = (N_EDGES / 4 + CHUNK_I4 - 1) / CHUNK_I4;   // 293
        pass_a<<<grid_a, BT, 0, stream>>>(edge_row, edge_col, edge_val,
                                          bucket_cursor, tmp_r, tmp_cv);
        pass_b<<<NB, BT, 0, stream>>>(bucket_ptr, tmp_r, tmp_cv, row_ptr, cv);

        // ---- init + 3 gather layers (bf16 x, fp32 acc) ----
        init_kernel<<<grid_f4, BT, 0, stream>>>(emb_user, emb_item, xA, acc);
        const int grid_rows = (N_NODES + 3) / 4;
        spmm_kernel<0><<<grid_rows, BT, 0, stream>>>(row_ptr, cv, xA, xB, acc);
        spmm_kernel<0><<<grid_rows, BT, 0, stream>>>(row_ptr, cv, xB, xA, acc);
        spmm_kernel<1><<<grid_rows, BT, 0, stream>>>(row_ptr, cv, xA, xB, acc);
    } else {
        // ---- fallback: atomic scatter path ----
        const size_t buf_elems = (size_t)N_NODES * EMB_DIM;
        const size_t buf_bytes = buf_elems * sizeof(float);
        float* bufA = (float*)d_ws;
        float* bufB = bufA + buf_elems;
        fb_init<<<grid_f4, BT, 0, stream>>>(emb_user, emb_item, bufA, acc);
        const long long scatter_threads = (long long)N_EDGES * 16;
        const int grid_sc = (int)((scatter_threads + BT - 1) / BT);
        float* cur = bufA;
        float* nxt = bufB;
        for (int layer = 0; layer < N_LAYERS; ++layer) {
            hipMemsetAsync(nxt, 0, buf_bytes, stream);
            scatter_kernel<<<grid_sc, BT, 0, stream>>>(edge_row, edge_col, edge_val, cur, nxt);
            if (layer == N_LAYERS - 1) add_kernel<true><<<grid_f4, BT, 0, stream>>>(nxt, acc);
            else                        add_kernel<false><<<grid_f4, BT, 0, stream>>>(nxt, acc);
            float* t = cur; cur = nxt; nxt = t;
        }
    }
}

// Round 4
// 428.083 us; speedup vs baseline: 28.4215x; 1.5146x over previous
//
#include <hip/hip_runtime.h>

#define N_USERS 100000
#define N_ITEMS 50000
#define N_NODES 150000
#define EMB_DIM 64
#define N_EDGES 4800000
#define N_LAYERS 3

#define NB 586            // ceil(150000 / 256) buckets, bucket = row >> 8
#define CHUNK_I4 4096     // 16384 edges per pass_a block

#define VAL_ENC (32.0f * 16383.0f)
#define VAL_DEC (1.0f / (32.0f * 16383.0f))

__device__ __forceinline__ ushort f2bf(float f) {
    unsigned int b = __float_as_uint(f);
    unsigned int r = (b + 0x7FFFu + ((b >> 16) & 1u)) >> 16;   // RNE
    return (ushort)r;
}
__device__ __forceinline__ float bf2f(ushort u) {
    return __uint_as_float(((unsigned int)u) << 16);
}
__device__ __forceinline__ uint pack_cv(int c, float v) {
    uint vq = (uint)(v * VAL_ENC + 0.5f);
    if (vq > 16383u) vq = 16383u;
    return ((uint)c << 14) | vq;
}

// ---------------------------------------------------------------------------
// init: x0 = bf16(concat(emb_user, emb_item))
// ---------------------------------------------------------------------------
__global__ void init_kernel(const float* __restrict__ emb_user,
                            const float* __restrict__ emb_item,
                            ushort* __restrict__ x0) {
    int i = blockIdx.x * blockDim.x + threadIdx.x;
    const int total = N_NODES * EMB_DIM / 4;
    if (i >= total) return;
    const int user_f4 = N_USERS * EMB_DIM / 4;
    float4 v;
    if (i < user_f4) v = reinterpret_cast<const float4*>(emb_user)[i];
    else             v = reinterpret_cast<const float4*>(emb_item)[i - user_f4];
    ushort4 h;
    h.x = f2bf(v.x); h.y = f2bf(v.y); h.z = f2bf(v.z); h.w = f2bf(v.w);
    reinterpret_cast<ushort4*>(x0)[i] = h;
}

// ---------------------------------------------------------------------------
// K1: global bucket histogram (LDS-staged)
// ---------------------------------------------------------------------------
__global__ void bucket_hist(const int* __restrict__ row, int* __restrict__ bucket_cnt) {
    __shared__ int cnt[NB];
    int t = threadIdx.x;
    for (int b = t; b < NB; b += 256) cnt[b] = 0;
    __syncthreads();
    int i = blockIdx.x * blockDim.x + t;
    int stride = gridDim.x * blockDim.x;
    for (int e = i; e < N_EDGES / 4; e += stride) {
        int4 r = reinterpret_cast<const int4*>(row)[e];
        atomicAdd(&cnt[r.x >> 8], 1);
        atomicAdd(&cnt[r.y >> 8], 1);
        atomicAdd(&cnt[r.z >> 8], 1);
        atomicAdd(&cnt[r.w >> 8], 1);
    }
    __syncthreads();
    for (int b = t; b < NB; b += 256) {
        int c = cnt[b];
        if (c) atomicAdd(&bucket_cnt[b], c);
    }
}

// ---------------------------------------------------------------------------
// K2: exclusive scan of 586 bucket counts (one 1024-thread block)
// ---------------------------------------------------------------------------
__global__ void bucket_scan(const int* __restrict__ bucket_cnt,
                            int* __restrict__ bucket_ptr,
                            int* __restrict__ bucket_cursor,
                            int* __restrict__ row_ptr) {
    __shared__ int lds[1024];
    int t = threadIdx.x;
    int v = (t < NB) ? bucket_cnt[t] : 0;
    lds[t] = v;
    __syncthreads();
    for (int off = 1; off < 1024; off <<= 1) {
        int x = (t >= off) ? lds[t - off] : 0;
        __syncthreads();
        lds[t] += x;
        __syncthreads();
    }
    int incl = lds[t];
    int excl = incl - v;
    if (t < NB) { bucket_ptr[t] = excl; bucket_cursor[t] = excl; }
    if (t == NB - 1) bucket_ptr[NB] = incl;
    if (t == 0) row_ptr[N_NODES] = N_EDGES;
}

// ---------------------------------------------------------------------------
// K3 (pass A): bin edges into bucket-contiguous regions; pack (col,val)->4B.
// ---------------------------------------------------------------------------
__global__ void pass_a(const int* __restrict__ row, const int* __restrict__ col,
                       const float* __restrict__ val,
                       int* __restrict__ bucket_cursor,
                       unsigned char* __restrict__ tmp_r, uint* __restrict__ tmp_cv) {
    __shared__ int cnt[NB];
    __shared__ int cur[NB];
    int t = threadIdx.x;
    int start = blockIdx.x * CHUNK_I4;
    int end = start + CHUNK_I4;
    if (end > N_EDGES / 4) end = N_EDGES / 4;
    for (int b = t; b < NB; b += 256) cnt[b] = 0;
    __syncthreads();
    for (int i = start + t; i < end; i += 256) {
        int4 r = reinterpret_cast<const int4*>(row)[i];
        atomicAdd(&cnt[r.x >> 8], 1);
        atomicAdd(&cnt[r.y >> 8], 1);
        atomicAdd(&cnt[r.z >> 8], 1);
        atomicAdd(&cnt[r.w >> 8], 1);
    }
    __syncthreads();
    for (int b = t; b < NB; b += 256) {
        int c = cnt[b];
        cur[b] = c ? atomicAdd(&bucket_cursor[b], c) : 0;
    }
    __syncthreads();
    for (int i = start + t; i < end; i += 256) {
        int4 r = reinterpret_cast<const int4*>(row)[i];
        int4 c = reinterpret_cast<const int4*>(col)[i];
        float4 v = reinterpret_cast<const float4*>(val)[i];
        int p;
        p = atomicAdd(&cur[r.x >> 8], 1); tmp_r[p] = (unsigned char)(r.x & 255); tmp_cv[p] = pack_cv(c.x, v.x);
        p = atomicAdd(&cur[r.y >> 8], 1); tmp_r[p] = (unsigned char)(r.y & 255); tmp_cv[p] = pack_cv(c.y, v.y);
        p = atomicAdd(&cur[r.z >> 8], 1); tmp_r[p] = (unsigned char)(r.z & 255); tmp_cv[p] = pack_cv(c.z, v.z);
        p = atomicAdd(&cur[r.w >> 8], 1); tmp_r[p] = (unsigned char)(r.w & 255); tmp_cv[p] = pack_cv(c.w, v.w);
    }
}

// ---------------------------------------------------------------------------
// K4 (pass B): per-bucket row sort; emits row_ptr + row-sorted packed cv.
// ---------------------------------------------------------------------------
__global__ void pass_b(const int* __restrict__ bucket_ptr,
                       const unsigned char* __restrict__ tmp_r,
                       const uint* __restrict__ tmp_cv,
                       int* __restrict__ row_ptr, uint* __restrict__ cv) {
    __shared__ int cnt[256];
    __shared__ int cur[256];
    __shared__ int wtot[4];
    int t = threadIdx.x;
    int b = blockIdx.x;
    int bp = bucket_ptr[b], be = bucket_ptr[b + 1];
    cnt[t] = 0;
    __syncthreads();
    for (int e = bp + t; e < be; e += 256) atomicAdd(&cnt[tmp_r[e]], 1);
    __syncthreads();
    int v = cnt[t];
    int lane = t & 63, wv = t >> 6;
    int x = v;
    for (int off = 1; off < 64; off <<= 1) {
        int y = __shfl_up(x, off, 64);
        if (lane >= off) x += y;
    }
    if (lane == 63) wtot[wv] = x;
    __syncthreads();
    int woff = 0;
    for (int w = 0; w < wv; ++w) woff += wtot[w];
    int excl = x + woff - v;
    int gr = (b << 8) + t;
    if (gr < N_NODES) row_ptr[gr] = bp + excl;
    cur[t] = bp + excl;
    __syncthreads();
    for (int e = bp + t; e < be; e += 256) {
        int r = tmp_r[e];
        int pos = atomicAdd(&cur[r], 1);
        cv[pos] = tmp_cv[e];
    }
}

// ---------------------------------------------------------------------------
// gather SpMM: one wave per row. Wave-wide cvp preload (64 edges/round),
// shfl-distributed addresses, 4 independent gathers per unrolled iter.
// MODE 0: y = bf16(A*x)
// MODE 1: out = (emb + y1 + y2 + A*x) * 0.25   (fused final combine)
// ---------------------------------------------------------------------------
template <int MODE>
__global__ void spmm_kernel(const int* __restrict__ row_ptr,
                            const uint* __restrict__ cvp,
                            const ushort* __restrict__ x,
                            ushort* __restrict__ y,
                            const float* __restrict__ emb_user,
                            const float* __restrict__ emb_item,
                            const ushort* __restrict__ y1,
                            const ushort* __restrict__ y2,
                            float* __restrict__ out) {
    int wave = threadIdx.x >> 6;
    int lane = threadIdx.x & 63;
    int r = blockIdx.x * 4 + wave;
    if (r >= N_NODES) return;
    int g = lane >> 4;   // edge-slot group
    int d = lane & 15;   // ushort4 slot within the embedding row
    int s = row_ptr[r];
    int deg = row_ptr[r + 1] - s;
    const ushort4* xu = reinterpret_cast<const ushort4*>(x);
    float4 a4 = make_float4(0.f, 0.f, 0.f, 0.f);

    for (int base = 0; base < deg; base += 64) {
        int nload = deg - base;
        if (nload > 64) nload = 64;
        // wave-wide coalesced preload of up to 64 packed edges
        uint mycv = cvp[s + base + (lane < nload ? lane : nload - 1)];
        int rounds4 = (nload + 15) >> 4;   // 1..4 unrolled-by-4 blocks
        for (int k4 = 0; k4 < rounds4; ++k4) {
            int i0 = (k4 << 4) + g;
            int i1 = i0 + 4, i2 = i0 + 8, i3 = i0 + 12;
            uint c0 = __shfl(mycv, i0, 64);
            uint c1 = __shfl(mycv, i1, 64);
            uint c2 = __shfl(mycv, i2, 64);
            uint c3 = __shfl(mycv, i3, 64);
            // 4 independent gathers
            ushort4 xv0 = xu[((c0 >> 14) << 4) + d];
            ushort4 xv1 = xu[((c1 >> 14) << 4) + d];
            ushort4 xv2 = xu[((c2 >> 14) << 4) + d];
            ushort4 xv3 = xu[((c3 >> 14) << 4) + d];
            float v0 = (i0 < nload) ? (float)(c0 & 16383u) * VAL_DEC : 0.f;
            float v1 = (i1 < nload) ? (float)(c1 & 16383u) * VAL_DEC : 0.f;
            float v2 = (i2 < nload) ? (float)(c2 & 16383u) * VAL_DEC : 0.f;
            float v3 = (i3 < nload) ? (float)(c3 & 16383u) * VAL_DEC : 0.f;
            a4.x += v0 * bf2f(xv0.x); a4.y += v0 * bf2f(xv0.y);
            a4.z += v0 * bf2f(xv0.z); a4.w += v0 * bf2f(xv0.w);
            a4.x += v1 * bf2f(xv1.x); a4.y += v1 * bf2f(xv1.y);
            a4.z += v1 * bf2f(xv1.z); a4.w += v1 * bf2f(xv1.w);
            a4.x += v2 * bf2f(xv2.x); a4.y += v2 * bf2f(xv2.y);
            a4.z += v2 * bf2f(xv2.z); a4.w += v2 * bf2f(xv2.w);
            a4.x += v3 * bf2f(xv3.x); a4.y += v3 * bf2f(xv3.y);
            a4.z += v3 * bf2f(xv3.z); a4.w += v3 * bf2f(xv3.w);
        }
    }
    // reduce the 4 edge-slot groups
    for (int off = 16; off <= 32; off <<= 1) {
        a4.x += __shfl_xor(a4.x, off, 64);
        a4.y += __shfl_xor(a4.y, off, 64);
        a4.z += __shfl_xor(a4.z, off, 64);
        a4.w += __shfl_xor(a4.w, off, 64);
    }
    if (g == 0) {
        int o = (r << 4) + d;
        if (MODE == 0) {
            ushort4 h;
            h.x = f2bf(a4.x); h.y = f2bf(a4.y); h.z = f2bf(a4.z); h.w = f2bf(a4.w);
            reinterpret_cast<ushort4*>(y)[o] = h;
        } else {
            const float4* eb = (r < N_USERS)
                ? reinterpret_cast<const float4*>(emb_user) + ((size_t)r << 4)
                : reinterpret_cast<const float4*>(emb_item) + ((size_t)(r - N_USERS) << 4);
            float4 ev = eb[d];
            ushort4 h1 = reinterpret_cast<const ushort4*>(y1)[o];
            ushort4 h2 = reinterpret_cast<const ushort4*>(y2)[o];
            float4 rr;
            rr.x = (ev.x + bf2f(h1.x) + bf2f(h2.x) + a4.x) * 0.25f;
            rr.y = (ev.y + bf2f(h1.y) + bf2f(h2.y) + a4.y) * 0.25f;
            rr.z = (ev.z + bf2f(h1.z) + bf2f(h2.z) + a4.z) * 0.25f;
            rr.w = (ev.w + bf2f(h1.w) + bf2f(h2.w) + a4.w) * 0.25f;
            reinterpret_cast<float4*>(out)[o] = rr;
        }
    }
}

// ---------------------------------------------------------------------------
// fallback (round-0) atomic path, used only if ws_size is too small
// ---------------------------------------------------------------------------
__global__ void fb_init(const float* __restrict__ emb_user,
                        const float* __restrict__ emb_item,
                        float* __restrict__ cur, float* __restrict__ acc) {
    int i = blockIdx.x * blockDim.x + threadIdx.x;
    const int total = N_NODES * EMB_DIM / 4;
    if (i >= total) return;
    const int user_f4 = N_USERS * EMB_DIM / 4;
    float4 v;
    if (i < user_f4) v = reinterpret_cast<const float4*>(emb_user)[i];
    else             v = reinterpret_cast<const float4*>(emb_item)[i - user_f4];
    reinterpret_cast<float4*>(cur)[i] = v;
    reinterpret_cast<float4*>(acc)[i] = v;
}

__global__ void scatter_kernel(const int* __restrict__ edge_row,
                               const int* __restrict__ edge_col,
                               const float* __restrict__ edge_val,
                               const float* __restrict__ x,
                               float* __restrict__ y) {
    long long tid = (long long)blockIdx.x * blockDim.x + threadIdx.x;
    long long e = tid >> 4;
    int sub = (int)(tid & 15);
    if (e >= N_EDGES) return;
    int r = edge_row[e];
    int c = edge_col[e];
    float v = edge_val[e];
    float4 xv = reinterpret_cast<const float4*>(x)[(long long)c * 16 + sub];
    float* dst = y + ((long long)r * EMB_DIM + sub * 4);
    atomicAdd(dst + 0, v * xv.x);
    atomicAdd(dst + 1, v * xv.y);
    atomicAdd(dst + 2, v * xv.z);
    atomicAdd(dst + 3, v * xv.w);
}

template <bool FINAL>
__global__ void add_kernel(const float* __restrict__ nxt, float* __restrict__ acc) {
    int i = blockIdx.x * blockDim.x + threadIdx.x;
    const int total = N_NODES * EMB_DIM / 4;
    if (i >= total) return;
    float4 a = reinterpret_cast<float4*>(acc)[i];
    float4 b = reinterpret_cast<const float4*>(nxt)[i];
    a.x += b.x; a.y += b.y; a.z += b.z; a.w += b.w;
    if (FINAL) {
        const float s = 1.0f / (N_LAYERS + 1);
        a.x *= s; a.y *= s; a.z *= s; a.w *= s;
    }
    reinterpret_cast<float4*>(acc)[i] = a;
}

// ---------------------------------------------------------------------------
extern "C" void kernel_launch(void* const* d_in, const int* in_sizes, int n_in,
                              void* d_out, int out_size, void* d_ws, size_t ws_size,
                              hipStream_t stream) {
    const float* emb_user = (const float*)d_in[0];
    const float* emb_item = (const float*)d_in[1];
    const int*   edge_row = (const int*)d_in[2];
    const int*   edge_col = (const int*)d_in[3];
    const float* edge_val = (const float*)d_in[4];
    float* out = (float*)d_out;

    const size_t x_bytes = (size_t)N_NODES * EMB_DIM * sizeof(ushort);   // 19.2 MB

    // ---- workspace layout ----
    char* base = (char*)d_ws;
    uint*   cv = (uint*)base;                                 // 19.2 MB
    ushort* x0 = (ushort*)(base + (size_t)N_EDGES * 4);       // 19.2 MB
    ushort* x1 = (ushort*)((char*)x0 + x_bytes);              // 19.2 MB
    ushort* x2 = (ushort*)((char*)x1 + x_bytes);              // 19.2 MB
    char* meta = (char*)x2 + x_bytes;
    int* row_ptr       = (int*)meta;                          // N_NODES+1
    int* bucket_cnt    = row_ptr + N_NODES + 2;
    int* bucket_ptr    = bucket_cnt + NB;                     // NB+1
    int* bucket_cursor = bucket_ptr + NB + 1;
    size_t need = (size_t)((char*)(bucket_cursor + NB) - base);
    // tmp arrays alias x0/x1 (dead before init_kernel runs)
    unsigned char* tmp_r  = (unsigned char*)x0;               // 4.8 MB
    uint*          tmp_cv = (uint*)x1;                        // 19.2 MB

    const int BT = 256;
    const int total_f4 = N_NODES * EMB_DIM / 4;
    const int grid_f4 = (total_f4 + BT - 1) / BT;

    if (ws_size >= need) {
        // ---- bucketed counting sort -> row-sorted packed cv + row_ptr ----
        hipMemsetAsync(bucket_cnt, 0, NB * sizeof(int), stream);
        bucket_hist<<<512, BT, 0, stream>>>(edge_row, bucket_cnt);
        bucket_scan<<<1, 1024, 0, stream>>>(bucket_cnt, bucket_ptr, bucket_cursor, row_ptr);
        const int grid_a = (N_EDGES / 4 + CHUNK_I4 - 1) / CHUNK_I4;   // 293
        pass_a<<<grid_a, BT, 0, stream>>>(edge_row, edge_col, edge_val,
                                          bucket_cursor, tmp_r, tmp_cv);
        pass_b<<<NB, BT, 0, stream>>>(bucket_ptr, tmp_r, tmp_cv, row_ptr, cv);

        // ---- init + 3 gather layers ----
        init_kernel<<<grid_f4, BT, 0, stream>>>(emb_user, emb_item, x0);
        const int grid_rows = (N_NODES + 3) / 4;
        spmm_kernel<0><<<grid_rows, BT, 0, stream>>>(row_ptr, cv, x0, x1,
                                                     nullptr, nullptr, nullptr, nullptr, nullptr);
        spmm_kernel<0><<<grid_rows, BT, 0, stream>>>(row_ptr, cv, x1, x2,
                                                     nullptr, nullptr, nullptr, nullptr, nullptr);
        spmm_kernel<1><<<grid_rows, BT, 0, stream>>>(row_ptr, cv, x2, nullptr,
                                                     emb_user, emb_item, x1, x2, out);
    } else {
        // ---- fallback: atomic scatter path ----
        const size_t buf_elems = (size_t)N_NODES * EMB_DIM;
        const size_t buf_bytes = buf_elems * sizeof(float);
        float* bufA = (float*)d_ws;
        float* bufB = bufA + buf_elems;
        fb_init<<<grid_f4, BT, 0, stream>>>(emb_user, emb_item, bufA, out);
        const long long scatter_threads = (long long)N_EDGES * 16;
        const int grid_sc = (int)((scatter_threads + BT - 1) / BT);
        float* cur = bufA;
        float* nxt = bufB;
        for (int layer = 0; layer < N_LAYERS; ++layer) {
            hipMemsetAsync(nxt, 0, buf_bytes, stream);
            scatter_kernel<<<grid_sc, BT, 0, stream>>>(edge_row, edge_col, edge_val, cur, nxt);
            if (layer == N_LAYERS - 1) add_kernel<true><<<grid_f4, BT, 0, stream>>>(nxt, out);
            else                        add_kernel<false><<<grid_f4, BT, 0, stream>>>(nxt, out);
            float* t = cur; cur = nxt; nxt = t;
        }
    }
}

// Round 5
// 384.158 us; speedup vs baseline: 31.6712x; 1.1143x over previous
//
#include <hip/hip_runtime.h>

#define N_USERS 100000
#define N_ITEMS 50000
#define N_NODES 150000
#define EMB_DIM 64
#define N_EDGES 4800000
#define N_LAYERS 3

#define NB 586            // ceil(150000 / 256) buckets, bucket = row >> 8
#define PA_BLOCK 512
#define PA_CHUNK_I4 2048  // 8192 edges per pass_a block -> 586 blocks

#define VAL_ENC (32.0f * 16383.0f)
#define VAL_DEC (1.0f / (32.0f * 16383.0f))

__device__ __forceinline__ ushort f2bf(float f) {
    unsigned int b = __float_as_uint(f);
    unsigned int r = (b + 0x7FFFu + ((b >> 16) & 1u)) >> 16;   // RNE
    return (ushort)r;
}
__device__ __forceinline__ float bf2f(ushort u) {
    return __uint_as_float(((unsigned int)u) << 16);
}
__device__ __forceinline__ uint pack_cv(int c, float v) {
    uint vq = (uint)(v * VAL_ENC + 0.5f);
    if (vq > 16383u) vq = 16383u;
    return ((uint)c << 14) | vq;
}

// ---------------------------------------------------------------------------
// init: x0 = bf16(concat(emb_user, emb_item))
// ---------------------------------------------------------------------------
__global__ void init_kernel(const float* __restrict__ emb_user,
                            const float* __restrict__ emb_item,
                            ushort* __restrict__ x0) {
    int i = blockIdx.x * blockDim.x + threadIdx.x;
    const int total = N_NODES * EMB_DIM / 4;
    if (i >= total) return;
    const int user_f4 = N_USERS * EMB_DIM / 4;
    float4 v;
    if (i < user_f4) v = reinterpret_cast<const float4*>(emb_user)[i];
    else             v = reinterpret_cast<const float4*>(emb_item)[i - user_f4];
    ushort4 h;
    h.x = f2bf(v.x); h.y = f2bf(v.y); h.z = f2bf(v.z); h.w = f2bf(v.w);
    reinterpret_cast<ushort4*>(x0)[i] = h;
}

// ---------------------------------------------------------------------------
// K1: global bucket histogram (LDS-staged)
// ---------------------------------------------------------------------------
__global__ void bucket_hist(const int* __restrict__ row, int* __restrict__ bucket_cnt) {
    __shared__ int cnt[NB];
    int t = threadIdx.x;
    for (int b = t; b < NB; b += 256) cnt[b] = 0;
    __syncthreads();
    int i = blockIdx.x * blockDim.x + t;
    int stride = gridDim.x * blockDim.x;
    for (int e = i; e < N_EDGES / 4; e += stride) {
        int4 r = reinterpret_cast<const int4*>(row)[e];
        atomicAdd(&cnt[r.x >> 8], 1);
        atomicAdd(&cnt[r.y >> 8], 1);
        atomicAdd(&cnt[r.z >> 8], 1);
        atomicAdd(&cnt[r.w >> 8], 1);
    }
    __syncthreads();
    for (int b = t; b < NB; b += 256) {
        int c = cnt[b];
        if (c) atomicAdd(&bucket_cnt[b], c);
    }
}

// ---------------------------------------------------------------------------
// K2: exclusive scan of 586 bucket counts (one 1024-thread block)
// ---------------------------------------------------------------------------
__global__ void bucket_scan(const int* __restrict__ bucket_cnt,
                            int* __restrict__ bucket_ptr,
                            int* __restrict__ bucket_cursor,
                            int* __restrict__ row_ptr) {
    __shared__ int lds[1024];
    int t = threadIdx.x;
    int v = (t < NB) ? bucket_cnt[t] : 0;
    lds[t] = v;
    __syncthreads();
    for (int off = 1; off < 1024; off <<= 1) {
        int x = (t >= off) ? lds[t - off] : 0;
        __syncthreads();
        lds[t] += x;
        __syncthreads();
    }
    int incl = lds[t];
    int excl = incl - v;
    if (t < NB) { bucket_ptr[t] = excl; bucket_cursor[t] = excl; }
    if (t == NB - 1) bucket_ptr[NB] = incl;
    if (t == 0) row_ptr[N_NODES] = N_EDGES;
}

// ---------------------------------------------------------------------------
// K3 (pass A): bin edges into bucket-contiguous regions.
// 512-thread blocks, 8192-edge chunks; single 8B record {cv, row&255}.
// ---------------------------------------------------------------------------
__global__ void __launch_bounds__(PA_BLOCK)
pass_a(const int* __restrict__ row, const int* __restrict__ col,
       const float* __restrict__ val,
       int* __restrict__ bucket_cursor,
       uint2* __restrict__ tmp) {
    __shared__ int cnt[NB];
    __shared__ int cur[NB];
    int t = threadIdx.x;
    int start = blockIdx.x * PA_CHUNK_I4;
    int end = start + PA_CHUNK_I4;
    if (end > N_EDGES / 4) end = N_EDGES / 4;
    for (int b = t; b < NB; b += PA_BLOCK) cnt[b] = 0;
    __syncthreads();
    for (int i = start + t; i < end; i += PA_BLOCK) {
        int4 r = reinterpret_cast<const int4*>(row)[i];
        atomicAdd(&cnt[r.x >> 8], 1);
        atomicAdd(&cnt[r.y >> 8], 1);
        atomicAdd(&cnt[r.z >> 8], 1);
        atomicAdd(&cnt[r.w >> 8], 1);
    }
    __syncthreads();
    for (int b = t; b < NB; b += PA_BLOCK) {
        int c = cnt[b];
        cur[b] = c ? atomicAdd(&bucket_cursor[b], c) : 0;
    }
    __syncthreads();
    for (int i = start + t; i < end; i += PA_BLOCK) {
        int4 r = reinterpret_cast<const int4*>(row)[i];
        int4 c = reinterpret_cast<const int4*>(col)[i];
        float4 v = reinterpret_cast<const float4*>(val)[i];
        int p;
        p = atomicAdd(&cur[r.x >> 8], 1); tmp[p] = make_uint2(pack_cv(c.x, v.x), (uint)(r.x & 255));
        p = atomicAdd(&cur[r.y >> 8], 1); tmp[p] = make_uint2(pack_cv(c.y, v.y), (uint)(r.y & 255));
        p = atomicAdd(&cur[r.z >> 8], 1); tmp[p] = make_uint2(pack_cv(c.z, v.z), (uint)(r.z & 255));
        p = atomicAdd(&cur[r.w >> 8], 1); tmp[p] = make_uint2(pack_cv(c.w, v.w), (uint)(r.w & 255));
    }
}

// ---------------------------------------------------------------------------
// K4 (pass B): per-bucket row sort; emits row_ptr + row-sorted packed cv.
// ---------------------------------------------------------------------------
__global__ void pass_b(const int* __restrict__ bucket_ptr,
                       const uint2* __restrict__ tmp,
                       int* __restrict__ row_ptr, uint* __restrict__ cv) {
    __shared__ int cnt[256];
    __shared__ int cur[256];
    __shared__ int wtot[4];
    int t = threadIdx.x;
    int b = blockIdx.x;
    int bp = bucket_ptr[b], be = bucket_ptr[b + 1];
    cnt[t] = 0;
    __syncthreads();
    for (int e = bp + t; e < be; e += 256) atomicAdd(&cnt[tmp[e].y], 1);
    __syncthreads();
    int v = cnt[t];
    int lane = t & 63, wv = t >> 6;
    int x = v;
    for (int off = 1; off < 64; off <<= 1) {
        int y = __shfl_up(x, off, 64);
        if (lane >= off) x += y;
    }
    if (lane == 63) wtot[wv] = x;
    __syncthreads();
    int woff = 0;
    for (int w = 0; w < wv; ++w) woff += wtot[w];
    int excl = x + woff - v;
    int gr = (b << 8) + t;
    if (gr < N_NODES) row_ptr[gr] = bp + excl;
    cur[t] = bp + excl;
    __syncthreads();
    for (int e = bp + t; e < be; e += 256) {
        uint2 rec = tmp[e];
        int pos = atomicAdd(&cur[rec.y], 1);
        cv[pos] = rec.x;
    }
}

// ---------------------------------------------------------------------------
// gather SpMM: one wave per row. Wave-wide cvp preload (64 edges/round),
// shfl-distributed addresses, 4 independent gathers per unrolled iter.
// MODE 0: y = bf16(A*x)
// MODE 1: out = (emb + y1 + y2 + A*x) * 0.25   (fused final combine)
// ---------------------------------------------------------------------------
template <int MODE>
__global__ void spmm_kernel(const int* __restrict__ row_ptr,
                            const uint* __restrict__ cvp,
                            const ushort* __restrict__ x,
                            ushort* __restrict__ y,
                            const float* __restrict__ emb_user,
                            const float* __restrict__ emb_item,
                            const ushort* __restrict__ y1,
                            const ushort* __restrict__ y2,
                            float* __restrict__ out) {
    int wave = threadIdx.x >> 6;
    int lane = threadIdx.x & 63;
    int r = blockIdx.x * 4 + wave;
    if (r >= N_NODES) return;
    int g = lane >> 4;   // edge-slot group
    int d = lane & 15;   // ushort4 slot within the embedding row
    int s = row_ptr[r];
    int deg = row_ptr[r + 1] - s;
    const ushort4* xu = reinterpret_cast<const ushort4*>(x);
    float4 a4 = make_float4(0.f, 0.f, 0.f, 0.f);

    for (int base = 0; base < deg; base += 64) {
        int nload = deg - base;
        if (nload > 64) nload = 64;
        uint mycv = cvp[s + base + (lane < nload ? lane : nload - 1)];
        int rounds4 = (nload + 15) >> 4;
        for (int k4 = 0; k4 < rounds4; ++k4) {
            int i0 = (k4 << 4) + g;
            int i1 = i0 + 4, i2 = i0 + 8, i3 = i0 + 12;
            uint c0 = __shfl(mycv, i0, 64);
            uint c1 = __shfl(mycv, i1, 64);
            uint c2 = __shfl(mycv, i2, 64);
            uint c3 = __shfl(mycv, i3, 64);
            ushort4 xv0 = xu[((c0 >> 14) << 4) + d];
            ushort4 xv1 = xu[((c1 >> 14) << 4) + d];
            ushort4 xv2 = xu[((c2 >> 14) << 4) + d];
            ushort4 xv3 = xu[((c3 >> 14) << 4) + d];
            float v0 = (i0 < nload) ? (float)(c0 & 16383u) * VAL_DEC : 0.f;
            float v1 = (i1 < nload) ? (float)(c1 & 16383u) * VAL_DEC : 0.f;
            float v2 = (i2 < nload) ? (float)(c2 & 16383u) * VAL_DEC : 0.f;
            float v3 = (i3 < nload) ? (float)(c3 & 16383u) * VAL_DEC : 0.f;
            a4.x += v0 * bf2f(xv0.x); a4.y += v0 * bf2f(xv0.y);
            a4.z += v0 * bf2f(xv0.z); a4.w += v0 * bf2f(xv0.w);
            a4.x += v1 * bf2f(xv1.x); a4.y += v1 * bf2f(xv1.y);
            a4.z += v1 * bf2f(xv1.z); a4.w += v1 * bf2f(xv1.w);
            a4.x += v2 * bf2f(xv2.x); a4.y += v2 * bf2f(xv2.y);
            a4.z += v2 * bf2f(xv2.z); a4.w += v2 * bf2f(xv2.w);
            a4.x += v3 * bf2f(xv3.x); a4.y += v3 * bf2f(xv3.y);
            a4.z += v3 * bf2f(xv3.z); a4.w += v3 * bf2f(xv3.w);
        }
    }
    for (int off = 16; off <= 32; off <<= 1) {
        a4.x += __shfl_xor(a4.x, off, 64);
        a4.y += __shfl_xor(a4.y, off, 64);
        a4.z += __shfl_xor(a4.z, off, 64);
        a4.w += __shfl_xor(a4.w, off, 64);
    }
    if (g == 0) {
        int o = (r << 4) + d;
        if (MODE == 0) {
            ushort4 h;
            h.x = f2bf(a4.x); h.y = f2bf(a4.y); h.z = f2bf(a4.z); h.w = f2bf(a4.w);
            reinterpret_cast<ushort4*>(y)[o] = h;
        } else {
            const float4* eb = (r < N_USERS)
                ? reinterpret_cast<const float4*>(emb_user) + ((size_t)r << 4)
                : reinterpret_cast<const float4*>(emb_item) + ((size_t)(r - N_USERS) << 4);
            float4 ev = eb[d];
            ushort4 h1 = reinterpret_cast<const ushort4*>(y1)[o];
            ushort4 h2 = reinterpret_cast<const ushort4*>(y2)[o];
            float4 rr;
            rr.x = (ev.x + bf2f(h1.x) + bf2f(h2.x) + a4.x) * 0.25f;
            rr.y = (ev.y + bf2f(h1.y) + bf2f(h2.y) + a4.y) * 0.25f;
            rr.z = (ev.z + bf2f(h1.z) + bf2f(h2.z) + a4.z) * 0.25f;
            rr.w = (ev.w + bf2f(h1.w) + bf2f(h2.w) + a4.w) * 0.25f;
            reinterpret_cast<float4*>(out)[o] = rr;
        }
    }
}

// ---------------------------------------------------------------------------
// fallback (round-0) atomic path, used only if ws_size is too small
// ---------------------------------------------------------------------------
__global__ void fb_init(const float* __restrict__ emb_user,
                        const float* __restrict__ emb_item,
                        float* __restrict__ cur, float* __restrict__ acc) {
    int i = blockIdx.x * blockDim.x + threadIdx.x;
    const int total = N_NODES * EMB_DIM / 4;
    if (i >= total) return;
    const int user_f4 = N_USERS * EMB_DIM / 4;
    float4 v;
    if (i < user_f4) v = reinterpret_cast<const float4*>(emb_user)[i];
    else             v = reinterpret_cast<const float4*>(emb_item)[i - user_f4];
    reinterpret_cast<float4*>(cur)[i] = v;
    reinterpret_cast<float4*>(acc)[i] = v;
}

__global__ void scatter_kernel(const int* __restrict__ edge_row,
                               const int* __restrict__ edge_col,
                               const float* __restrict__ edge_val,
                               const float* __restrict__ x,
                               float* __restrict__ y) {
    long long tid = (long long)blockIdx.x * blockDim.x + threadIdx.x;
    long long e = tid >> 4;
    int sub = (int)(tid & 15);
    if (e >= N_EDGES) return;
    int r = edge_row[e];
    int c = edge_col[e];
    float v = edge_val[e];
    float4 xv = reinterpret_cast<const float4*>(x)[(long long)c * 16 + sub];
    float* dst = y + ((long long)r * EMB_DIM + sub * 4);
    atomicAdd(dst + 0, v * xv.x);
    atomicAdd(dst + 1, v * xv.y);
    atomicAdd(dst + 2, v * xv.z);
    atomicAdd(dst + 3, v * xv.w);
}

template <bool FINAL>
__global__ void add_kernel(const float* __restrict__ nxt, float* __restrict__ acc) {
    int i = blockIdx.x * blockDim.x + threadIdx.x;
    const int total = N_NODES * EMB_DIM / 4;
    if (i >= total) return;
    float4 a = reinterpret_cast<float4*>(acc)[i];
    float4 b = reinterpret_cast<const float4*>(nxt)[i];
    a.x += b.x; a.y += b.y; a.z += b.z; a.w += b.w;
    if (FINAL) {
        const float s = 1.0f / (N_LAYERS + 1);
        a.x *= s; a.y *= s; a.z *= s; a.w *= s;
    }
    reinterpret_cast<float4*>(acc)[i] = a;
}

// ---------------------------------------------------------------------------
extern "C" void kernel_launch(void* const* d_in, const int* in_sizes, int n_in,
                              void* d_out, int out_size, void* d_ws, size_t ws_size,
                              hipStream_t stream) {
    const float* emb_user = (const float*)d_in[0];
    const float* emb_item = (const float*)d_in[1];
    const int*   edge_row = (const int*)d_in[2];
    const int*   edge_col = (const int*)d_in[3];
    const float* edge_val = (const float*)d_in[4];
    float* out = (float*)d_out;

    const size_t x_bytes = (size_t)N_NODES * EMB_DIM * sizeof(ushort);   // 19.2 MB

    // ---- workspace layout ----
    char* base = (char*)d_ws;
    uint*   cv = (uint*)base;                                 // 19.2 MB
    ushort* x0 = (ushort*)(base + (size_t)N_EDGES * 4);       // 19.2 MB
    ushort* x1 = (ushort*)((char*)x0 + x_bytes);              // 19.2 MB
    ushort* x2 = (ushort*)((char*)x1 + x_bytes);              // 19.2 MB
    char* meta = (char*)x2 + x_bytes;
    int* row_ptr       = (int*)meta;                          // N_NODES+1
    int* bucket_cnt    = row_ptr + N_NODES + 2;
    int* bucket_ptr    = bucket_cnt + NB;                     // NB+1
    int* bucket_cursor = bucket_ptr + NB + 1;
    size_t need = (size_t)((char*)(bucket_cursor + NB) - base);
    // tmp records alias x0+x1 (dead before init_kernel runs)
    uint2* tmp = (uint2*)x0;                                  // 38.4 MB

    const int BT = 256;
    const int total_f4 = N_NODES * EMB_DIM / 4;
    const int grid_f4 = (total_f4 + BT - 1) / BT;

    if (ws_size >= need) {
        // ---- bucketed counting sort -> row-sorted packed cv + row_ptr ----
        hipMemsetAsync(bucket_cnt, 0, NB * sizeof(int), stream);
        bucket_hist<<<512, BT, 0, stream>>>(edge_row, bucket_cnt);
        bucket_scan<<<1, 1024, 0, stream>>>(bucket_cnt, bucket_ptr, bucket_cursor, row_ptr);
        const int grid_a = (N_EDGES / 4 + PA_CHUNK_I4 - 1) / PA_CHUNK_I4;   // 586
        pass_a<<<grid_a, PA_BLOCK, 0, stream>>>(edge_row, edge_col, edge_val,
                                                bucket_cursor, tmp);
        pass_b<<<NB, BT, 0, stream>>>(bucket_ptr, tmp, row_ptr, cv);

        // ---- init + 3 gather layers ----
        init_kernel<<<grid_f4, BT, 0, stream>>>(emb_user, emb_item, x0);
        const int grid_rows = (N_NODES + 3) / 4;
        spmm_kernel<0><<<grid_rows, BT, 0, stream>>>(row_ptr, cv, x0, x1,
                                                     nullptr, nullptr, nullptr, nullptr, nullptr);
        spmm_kernel<0><<<grid_rows, BT, 0, stream>>>(row_ptr, cv, x1, x2,
                                                     nullptr, nullptr, nullptr, nullptr, nullptr);
        spmm_kernel<1><<<grid_rows, BT, 0, stream>>>(row_ptr, cv, x2, nullptr,
                                                     emb_user, emb_item, x1, x2, out);
    } else {
        // ---- fallback: atomic scatter path ----
        const size_t buf_elems = (size_t)N_NODES * EMB_DIM;
        const size_t buf_bytes = buf_elems * sizeof(float);
        float* bufA = (float*)d_ws;
        float* bufB = bufA + buf_elems;
        fb_init<<<grid_f4, BT, 0, stream>>>(emb_user, emb_item, bufA, out);
        const long long scatter_threads = (long long)N_EDGES * 16;
        const int grid_sc = (int)((scatter_threads + BT - 1) / BT);
        float* cur = bufA;
        float* nxt = bufB;
        for (int layer = 0; layer < N_LAYERS; ++layer) {
            hipMemsetAsync(nxt, 0, buf_bytes, stream);
            scatter_kernel<<<grid_sc, BT, 0, stream>>>(edge_row, edge_col, edge_val, cur, nxt);
            if (layer == N_LAYERS - 1) add_kernel<true><<<grid_f4, BT, 0, stream>>>(nxt, out);
            else                        add_kernel<false><<<grid_f4, BT, 0, stream>>>(nxt, out);
            float* t = cur; cur = nxt; nxt = t;
        }
    }
}